// Round 2
// baseline (429.139 us; speedup 1.0000x reference)
//
#include <hip/hip_runtime.h>

// ---------------------------------------------------------------------------
// Net: conv(1->6,3x3,pad1)+relu+pool -> conv(6->4,6x6)+relu+pool ->
//      conv(4->2,3x3)+relu+pool -> flatten[200] -> fc1[200->400]+relu ->
//      fc2[400->200]+relu -> 100 heads of Linear chains 200->140->84->42->4
// B=1024, R=100, all float32.
// ---------------------------------------------------------------------------

#define NB 1024
#define NR 100

// conv1: x[B,1,98,98] -> out[B,6,49,49]   (conv 3x3 pad1 + relu + maxpool2)
__global__ __launch_bounds__(256) void conv1_k(const float* __restrict__ x,
        const float* __restrict__ w, const float* __restrict__ bias,
        float* __restrict__ out) {
    __shared__ float img[98*98];
    __shared__ float ws[54];
    __shared__ float bs[6];
    const int b = blockIdx.x;
    const int tid = threadIdx.x;
    const float* xb = x + (size_t)b * 9604;
    for (int i = tid; i < 2401; i += 256)
        ((float4*)img)[i] = ((const float4*)xb)[i];
    if (tid < 54) ws[tid] = w[tid];
    if (tid < 6) bs[tid] = bias[tid];
    __syncthreads();
    for (int pos = tid; pos < 2401; pos += 256) {
        const int py = pos / 49, px = pos % 49;
        const int y0 = 2*py - 1, x0 = 2*px - 1;
        float p[4][4];
        #pragma unroll
        for (int dy = 0; dy < 4; ++dy) {
            const int iy = y0 + dy;
            #pragma unroll
            for (int dx = 0; dx < 4; ++dx) {
                const int ix = x0 + dx;
                p[dy][dx] = (iy >= 0 && iy < 98 && ix >= 0 && ix < 98)
                            ? img[iy*98 + ix] : 0.f;
            }
        }
        #pragma unroll
        for (int c = 0; c < 6; ++c) {
            float v0 = bs[c], v1 = bs[c], v2 = bs[c], v3 = bs[c];
            #pragma unroll
            for (int ky = 0; ky < 3; ++ky) {
                #pragma unroll
                for (int kx = 0; kx < 3; ++kx) {
                    const float wv = ws[c*9 + ky*3 + kx];
                    v0 = fmaf(wv, p[ky  ][kx  ], v0);
                    v1 = fmaf(wv, p[ky  ][kx+1], v1);
                    v2 = fmaf(wv, p[ky+1][kx  ], v2);
                    v3 = fmaf(wv, p[ky+1][kx+1], v3);
                }
            }
            float m = fmaxf(fmaxf(v0, v1), fmaxf(v2, v3));
            out[((size_t)b*6 + c)*2401 + pos] = fmaxf(m, 0.f);
        }
    }
}

// conv2: in[B,6,49,49] -> out[B,4,22,22]  (conv 6x6 VALID + relu + maxpool2)
__global__ __launch_bounds__(256) void conv2_k(const float* __restrict__ in,
        const float* __restrict__ w, const float* __restrict__ bias,
        float* __restrict__ out) {
    __shared__ float sm[14406];     // 6*49*49
    __shared__ float ws[864];       // 4*6*36
    __shared__ float bs[4];
    const int b = blockIdx.x;
    const int tid = threadIdx.x;
    const float* src = in + (size_t)b * 14406;
    for (int i = tid; i < 7203; i += 256)
        ((float2*)sm)[i] = ((const float2*)src)[i];
    for (int i = tid; i < 864; i += 256) ws[i] = w[i];
    if (tid < 4) bs[tid] = bias[tid];
    __syncthreads();
    for (int pos = tid; pos < 484; pos += 256) {
        const int py = pos / 22, px = pos % 22;
        const int y0 = 2*py, x0 = 2*px;
        float acc[4][4];
        #pragma unroll
        for (int oc = 0; oc < 4; ++oc) {
            acc[oc][0] = acc[oc][1] = acc[oc][2] = acc[oc][3] = bs[oc];
        }
        #pragma unroll
        for (int ic = 0; ic < 6; ++ic) {
            float p[7][7];
            const float* base = sm + ic*2401 + y0*49 + x0;
            #pragma unroll
            for (int u = 0; u < 7; ++u)
                #pragma unroll
                for (int v = 0; v < 7; ++v)
                    p[u][v] = base[u*49 + v];
            #pragma unroll
            for (int oc = 0; oc < 4; ++oc) {
                const float* wp = ws + (oc*6 + ic)*36;
                #pragma unroll
                for (int ky = 0; ky < 6; ++ky) {
                    #pragma unroll
                    for (int kx = 0; kx < 6; ++kx) {
                        const float wv = wp[ky*6 + kx];
                        acc[oc][0] = fmaf(wv, p[ky  ][kx  ], acc[oc][0]);
                        acc[oc][1] = fmaf(wv, p[ky  ][kx+1], acc[oc][1]);
                        acc[oc][2] = fmaf(wv, p[ky+1][kx  ], acc[oc][2]);
                        acc[oc][3] = fmaf(wv, p[ky+1][kx+1], acc[oc][3]);
                    }
                }
            }
        }
        #pragma unroll
        for (int oc = 0; oc < 4; ++oc) {
            float m = fmaxf(fmaxf(acc[oc][0], acc[oc][1]),
                            fmaxf(acc[oc][2], acc[oc][3]));
            out[((size_t)b*4 + oc)*484 + pos] = fmaxf(m, 0.f);
        }
    }
}

// conv3: in[B,4,22,22] -> out[B,200]  (conv 3x3 VALID + relu + maxpool2 + flatten)
__global__ __launch_bounds__(256) void conv3_k(const float* __restrict__ in,
        const float* __restrict__ w, const float* __restrict__ bias,
        float* __restrict__ out) {
    __shared__ float sm[1936];      // 4*22*22
    __shared__ float ws[72];        // 2*4*9
    __shared__ float bs[2];
    const int b = blockIdx.x;
    const int tid = threadIdx.x;
    const float* src = in + (size_t)b * 1936;
    for (int i = tid; i < 484; i += 256)
        ((float4*)sm)[i] = ((const float4*)src)[i];
    if (tid < 72) ws[tid] = w[tid];
    if (tid < 2) bs[tid] = bias[tid];
    __syncthreads();
    if (tid < 200) {
        const int c = tid / 100;
        const int rem = tid % 100;
        const int py = rem / 10, px = rem % 10;
        const int y0 = 2*py, x0 = 2*px;
        float a0, a1, a2, a3;
        a0 = a1 = a2 = a3 = bs[c];
        #pragma unroll
        for (int ic = 0; ic < 4; ++ic) {
            float p[4][4];
            const float* base = sm + ic*484 + y0*22 + x0;
            #pragma unroll
            for (int u = 0; u < 4; ++u)
                #pragma unroll
                for (int v = 0; v < 4; ++v)
                    p[u][v] = base[u*22 + v];
            const float* wp = ws + (c*4 + ic)*9;
            #pragma unroll
            for (int ky = 0; ky < 3; ++ky) {
                #pragma unroll
                for (int kx = 0; kx < 3; ++kx) {
                    const float wv = wp[ky*3 + kx];
                    a0 = fmaf(wv, p[ky  ][kx  ], a0);
                    a1 = fmaf(wv, p[ky  ][kx+1], a1);
                    a2 = fmaf(wv, p[ky+1][kx  ], a2);
                    a3 = fmaf(wv, p[ky+1][kx+1], a3);
                }
            }
        }
        float m = fmaxf(fmaxf(a0, a1), fmaxf(a2, a3));
        out[(size_t)b*200 + tid] = fmaxf(m, 0.f);
    }
}

// Generic (optionally r-batched) GEMM: C[r][m][n] = relu(sum_k A[r?][m][k]*W[r][k][n] + b[r][n])
// Block tile 128(M) x 64(N), 256 threads, 8x4 micro-tile, K chunked by 32 in LDS.
// VEC: true iff N % 4 == 0 (vectorized W/bias/C access).
template<bool VEC>
__global__ __launch_bounds__(256) void gemm_k(
        const float* __restrict__ A, long a_rstride,
        const float* __restrict__ W, const float* __restrict__ bias,
        float* __restrict__ C, int M, int N, int K, int do_relu) {
    __shared__ float As[32][132];   // [k][m], padded to kill write conflicts
    __shared__ float Ws[32][64];    // [k][n]
    const int r  = blockIdx.z;
    const int m0 = blockIdx.y * 128;
    const int n0 = blockIdx.x * 64;
    const float* Ab = A + (long)r * a_rstride;
    const float* Wb = W + (long)r * K * N;
    const float* bb = bias + (long)r * N;
    float* Cb = C + (long)r * M * N;
    const int tid = threadIdx.x;
    const int ti = tid >> 4, tj = tid & 15;
    float acc[8][4];
    #pragma unroll
    for (int i = 0; i < 8; ++i)
        #pragma unroll
        for (int j = 0; j < 4; ++j) acc[i][j] = 0.f;

    for (int k0 = 0; k0 < K; k0 += 32) {
        // stage A chunk (128 rows x 32 k), transposed into As[k][m]
        #pragma unroll
        for (int i = 0; i < 4; ++i) {
            const int f = tid + i*256;          // float4 id 0..1023
            const int m = f >> 3, kg = f & 7;
            const int kk = kg*4;
            float4 v = make_float4(0.f, 0.f, 0.f, 0.f);
            if (k0 + kk < K)                    // K%4==0 -> all-or-nothing
                v = *(const float4*)(Ab + (long)(m0 + m)*K + k0 + kk);
            As[kk+0][m] = v.x;
            As[kk+1][m] = v.y;
            As[kk+2][m] = v.z;
            As[kk+3][m] = v.w;
        }
        // stage W chunk (32 k x 64 n)
        #pragma unroll
        for (int i = 0; i < 2; ++i) {
            const int f = tid + i*256;          // float4 id 0..511
            const int kk = f >> 4, cg = f & 15;
            const int n = n0 + cg*4;
            float4 v = make_float4(0.f, 0.f, 0.f, 0.f);
            if (k0 + kk < K) {
                const float* wp = Wb + (long)(k0 + kk)*N;
                if (VEC) {
                    if (n < N) v = *(const float4*)(wp + n);
                } else {
                    if (n+0 < N) v.x = wp[n+0];
                    if (n+1 < N) v.y = wp[n+1];
                    if (n+2 < N) v.z = wp[n+2];
                    if (n+3 < N) v.w = wp[n+3];
                }
            }
            *(float4*)&Ws[kk][cg*4] = v;
        }
        __syncthreads();
        #pragma unroll
        for (int kk = 0; kk < 32; ++kk) {
            float a[8], wv[4];
            *(float4*)&a[0] = *(const float4*)&As[kk][ti*8];
            *(float4*)&a[4] = *(const float4*)&As[kk][ti*8 + 4];
            *(float4*)&wv[0] = *(const float4*)&Ws[kk][tj*4];
            #pragma unroll
            for (int i = 0; i < 8; ++i)
                #pragma unroll
                for (int j = 0; j < 4; ++j)
                    acc[i][j] = fmaf(a[i], wv[j], acc[i][j]);
        }
        __syncthreads();
    }

    const int n = n0 + tj*4;
    float bv[4] = {0.f, 0.f, 0.f, 0.f};
    if (VEC) {
        if (n < N) *(float4*)bv = *(const float4*)(bb + n);
    } else {
        #pragma unroll
        for (int e = 0; e < 4; ++e) if (n + e < N) bv[e] = bb[n + e];
    }
    #pragma unroll
    for (int i = 0; i < 8; ++i) {
        const long m = m0 + ti*8 + i;
        float v[4];
        #pragma unroll
        for (int j = 0; j < 4; ++j) {
            v[j] = acc[i][j] + bv[j];
            if (do_relu) v[j] = fmaxf(v[j], 0.f);
        }
        if (VEC) {
            if (n < N) *(float4*)(Cb + m*N + n) = *(float4*)v;
        } else {
            #pragma unroll
            for (int j = 0; j < 4; ++j)
                if (n + j < N) Cb[m*N + n + j] = v[j];
        }
    }
}

// head L4: out[b, r*4+j] = sum_d g3[r,b,d]*w4[r,d,j] + b4[r,j]   (no relu)
__global__ __launch_bounds__(256) void head4_k(
        const float* __restrict__ A,    // [R][B][42]
        const float* __restrict__ W,    // [R][42][4]
        const float* __restrict__ bias, // [R][4]
        float* __restrict__ out) {      // [B][400]
    const int r = blockIdx.x >> 2;                       // 4 blocks per r
    const int b = (blockIdx.x & 3) * 256 + threadIdx.x;  // 0..1023
    const float* a = A + ((long)r * NB + b) * 42;
    const float* w = W + (long)r * 168;
    float4 acc = *(const float4*)(bias + r*4);
    #pragma unroll
    for (int d = 0; d < 42; ++d) {
        const float av = a[d];
        const float4 wv = *(const float4*)(w + d*4);
        acc.x = fmaf(av, wv.x, acc.x);
        acc.y = fmaf(av, wv.y, acc.y);
        acc.z = fmaf(av, wv.z, acc.z);
        acc.w = fmaf(av, wv.w, acc.w);
    }
    *(float4*)(out + (long)b*400 + r*4) = acc;
}

extern "C" void kernel_launch(void* const* d_in, const int* in_sizes, int n_in,
                              void* d_out, int out_size, void* d_ws, size_t ws_size,
                              hipStream_t stream) {
    const float* x    = (const float*)d_in[0];
    const float* c1w  = (const float*)d_in[1];
    const float* c1b  = (const float*)d_in[2];
    const float* c2w  = (const float*)d_in[3];
    const float* c2b  = (const float*)d_in[4];
    const float* c3w  = (const float*)d_in[5];
    const float* c3b  = (const float*)d_in[6];
    const float* fc1w = (const float*)d_in[7];
    const float* fc1b = (const float*)d_in[8];
    const float* fc2w = (const float*)d_in[9];
    const float* fc2b = (const float*)d_in[10];
    const float* h1w  = (const float*)d_in[11];
    const float* h1b  = (const float*)d_in[12];
    const float* h2w  = (const float*)d_in[13];
    const float* h2b  = (const float*)d_in[14];
    const float* h3w  = (const float*)d_in[15];
    const float* h3b  = (const float*)d_in[16];
    const float* h4w  = (const float*)d_in[17];
    const float* h4b  = (const float*)d_in[18];
    float* out = (float*)d_out;

    // workspace regions (aliased by liveness):
    //  region0: t1[B,6,49,49] (59.0MB) -> g1[R,B,140] (57.3MB) -> g3[R,B,42] (17.2MB)
    //  region1: t2[B,4,22,22] (7.9MB)  -> g2[R,B,84] (34.4MB)
    //  region2: t3[B,200] -> f2[B,200]
    //  region3: f1[B,400]
    char* ws = (char*)d_ws;
    const size_t off1 = (size_t)NB*6*2401*sizeof(float);          // 59,006,976
    const size_t off2 = off1 + (size_t)NR*NB*84*sizeof(float);    // +34,406,400
    const size_t off3 = off2 + (size_t)NB*200*sizeof(float);      // +819,200
    float* t1 = (float*)(ws);
    float* t2 = (float*)(ws + off1);
    float* t3 = (float*)(ws + off2);
    float* f1 = (float*)(ws + off3);
    float* f2 = t3;   // t3 dead after fc1
    float* g1 = t1;   // t1 dead after conv2
    float* g2 = t2;   // t2 dead after conv3
    float* g3 = t1;   // g1 dead after head L2

    conv1_k<<<NB, 256, 0, stream>>>(x, c1w, c1b, t1);
    conv2_k<<<NB, 256, 0, stream>>>(t1, c2w, c2b, t2);
    conv3_k<<<NB, 256, 0, stream>>>(t2, c3w, c3b, t3);

    // fc1: [1024,200] x [200,400] -> f1
    gemm_k<true><<<dim3(7, 8, 1), 256, 0, stream>>>(t3, 0L, fc1w, fc1b, f1,
                                                    NB, 400, 200, 1);
    // fc2: [1024,400] x [400,200] -> f2
    gemm_k<true><<<dim3(4, 8, 1), 256, 0, stream>>>(f1, 0L, fc2w, fc2b, f2,
                                                    NB, 200, 400, 1);
    // head L1: shared A (f2), W[r]=200x140 -> g1[R,B,140]
    gemm_k<true><<<dim3(3, 8, NR), 256, 0, stream>>>(f2, 0L, h1w, h1b, g1,
                                                     NB, 140, 200, 1);
    // head L2: A=g1[r], W[r]=140x84 -> g2[R,B,84]
    gemm_k<true><<<dim3(2, 8, NR), 256, 0, stream>>>(g1, (long)NB*140, h2w, h2b, g2,
                                                     NB, 84, 140, 1);
    // head L3: A=g2[r], W[r]=84x42 -> g3[R,B,42]  (N=42 not /4 -> scalar path)
    gemm_k<false><<<dim3(1, 8, NR), 256, 0, stream>>>(g2, (long)NB*84, h3w, h3b, g3,
                                                      NB, 42, 84, 1);
    // head L4 + interleaved output write
    head4_k<<<NR*4, 256, 0, stream>>>(g3, h4w, h4b, out);
    (void)in_sizes; (void)n_in; (void)out_size; (void)ws_size;
}

// Round 3
// 354.834 us; speedup vs baseline: 1.2094x; 1.2094x over previous
//
#include <hip/hip_runtime.h>

#define NB 1024
#define NR 100

// ---------------------------------------------------------------------------
// conv1: x[B,1,98,98] -> out[B,6,49,49]   (conv 3x3 pad1 + relu + maxpool2)
// ---------------------------------------------------------------------------
__global__ __launch_bounds__(256) void conv1_k(const float* __restrict__ x,
        const float* __restrict__ w, const float* __restrict__ bias,
        float* __restrict__ out) {
    __shared__ float img[98*98];
    __shared__ float ws[54];
    __shared__ float bs[6];
    const int b = blockIdx.x;
    const int tid = threadIdx.x;
    const float* xb = x + (size_t)b * 9604;
    for (int i = tid; i < 2401; i += 256)
        ((float4*)img)[i] = ((const float4*)xb)[i];
    if (tid < 54) ws[tid] = w[tid];
    if (tid < 6) bs[tid] = bias[tid];
    __syncthreads();
    for (int pos = tid; pos < 2401; pos += 256) {
        const int py = pos / 49, px = pos % 49;
        const int y0 = 2*py - 1, x0 = 2*px - 1;
        float p[4][4];
        #pragma unroll
        for (int dy = 0; dy < 4; ++dy) {
            const int iy = y0 + dy;
            #pragma unroll
            for (int dx = 0; dx < 4; ++dx) {
                const int ix = x0 + dx;
                p[dy][dx] = (iy >= 0 && iy < 98 && ix >= 0 && ix < 98)
                            ? img[iy*98 + ix] : 0.f;
            }
        }
        #pragma unroll
        for (int c = 0; c < 6; ++c) {
            float v0 = bs[c], v1 = bs[c], v2 = bs[c], v3 = bs[c];
            #pragma unroll
            for (int ky = 0; ky < 3; ++ky) {
                #pragma unroll
                for (int kx = 0; kx < 3; ++kx) {
                    const float wv = ws[c*9 + ky*3 + kx];
                    v0 = fmaf(wv, p[ky  ][kx  ], v0);
                    v1 = fmaf(wv, p[ky  ][kx+1], v1);
                    v2 = fmaf(wv, p[ky+1][kx  ], v2);
                    v3 = fmaf(wv, p[ky+1][kx+1], v3);
                }
            }
            float m = fmaxf(fmaxf(v0, v1), fmaxf(v2, v3));
            out[((size_t)b*6 + c)*2401 + pos] = fmaxf(m, 0.f);
        }
    }
}

// ---------------------------------------------------------------------------
// conv2: in[B,6,49,49] -> out[B,4,22,22]  (conv 6x6 VALID + relu + maxpool2)
// 4 blocks per image (2x2 spatial quadrants), 2-oc micro, low LDS/VGPR.
// ---------------------------------------------------------------------------
__global__ __launch_bounds__(256, 4) void conv2_k(const float* __restrict__ in,
        const float* __restrict__ w, const float* __restrict__ bias,
        float* __restrict__ out) {
    __shared__ float smc[6*27*28];  // [ic][27 rows][28 (27 cols + pad)]
    __shared__ float ws[864];       // 4*6*36
    __shared__ float bs[4];
    const int blk = blockIdx.x;
    const int b  = blk >> 2;
    const int qy = (blk >> 1) & 1, qx = blk & 1;
    const int r0 = qy*22, c0 = qx*22;
    const int tid = threadIdx.x;
    const float* src = in + (size_t)b * 14406;
    for (int idx = tid; idx < 6*27*27; idx += 256) {
        const int ic  = idx / 729;
        const int rem = idx - ic*729;
        const int rr  = rem / 27;
        const int cc  = rem - rr*27;
        smc[ic*756 + rr*28 + cc] = src[ic*2401 + (r0+rr)*49 + c0 + cc];
    }
    for (int i = tid; i < 864; i += 256) ws[i] = w[i];
    if (tid < 4) bs[tid] = bias[tid];
    __syncthreads();
    if (tid < 242) {
        const int ocg = tid / 121;            // 0..1 -> oc pair
        const int p   = tid - ocg*121;
        const int py  = p / 11, px = p - py*11;
        const int y0  = 2*py, x0 = 2*px;      // local coords
        float acc[2][4];
        #pragma unroll
        for (int o = 0; o < 2; ++o) {
            const float bv = bs[ocg*2 + o];
            acc[o][0] = acc[o][1] = acc[o][2] = acc[o][3] = bv;
        }
        #pragma unroll
        for (int ic = 0; ic < 6; ++ic) {
            float pt[7][7];
            const float* baseр = smc + ic*756 + y0*28 + x0;
            #pragma unroll
            for (int u = 0; u < 7; ++u) {
                const float* rb = baseр + u*28;   // 8B-aligned (all terms even)
                *(float2*)&pt[u][0] = *(const float2*)&rb[0];
                *(float2*)&pt[u][2] = *(const float2*)&rb[2];
                *(float2*)&pt[u][4] = *(const float2*)&rb[4];
                pt[u][6] = rb[6];
            }
            #pragma unroll
            for (int o = 0; o < 2; ++o) {
                const float* wp = ws + ((ocg*2 + o)*6 + ic)*36;
                #pragma unroll
                for (int ky = 0; ky < 6; ++ky) {
                    #pragma unroll
                    for (int kx = 0; kx < 6; ++kx) {
                        const float wv = wp[ky*6 + kx];
                        acc[o][0] = fmaf(wv, pt[ky  ][kx  ], acc[o][0]);
                        acc[o][1] = fmaf(wv, pt[ky  ][kx+1], acc[o][1]);
                        acc[o][2] = fmaf(wv, pt[ky+1][kx  ], acc[o][2]);
                        acc[o][3] = fmaf(wv, pt[ky+1][kx+1], acc[o][3]);
                    }
                }
            }
        }
        const int PY = qy*11 + py, PX = qx*11 + px;
        #pragma unroll
        for (int o = 0; o < 2; ++o) {
            const int oc = ocg*2 + o;
            float m = fmaxf(fmaxf(acc[o][0], acc[o][1]),
                            fmaxf(acc[o][2], acc[o][3]));
            out[(((size_t)b*4 + oc)*22 + PY)*22 + PX] = fmaxf(m, 0.f);
        }
    }
}

// ---------------------------------------------------------------------------
// conv3: in[B,4,22,22] -> out[B,200]  (conv 3x3 VALID + relu + maxpool2)
// ---------------------------------------------------------------------------
__global__ __launch_bounds__(256) void conv3_k(const float* __restrict__ in,
        const float* __restrict__ w, const float* __restrict__ bias,
        float* __restrict__ out) {
    __shared__ float sm[1936];
    __shared__ float ws[72];
    __shared__ float bs[2];
    const int b = blockIdx.x;
    const int tid = threadIdx.x;
    const float* src = in + (size_t)b * 1936;
    for (int i = tid; i < 484; i += 256)
        ((float4*)sm)[i] = ((const float4*)src)[i];
    if (tid < 72) ws[tid] = w[tid];
    if (tid < 2) bs[tid] = bias[tid];
    __syncthreads();
    if (tid < 200) {
        const int c = tid / 100;
        const int rem = tid % 100;
        const int py = rem / 10, px = rem % 10;
        const int y0 = 2*py, x0 = 2*px;
        float a0, a1, a2, a3;
        a0 = a1 = a2 = a3 = bs[c];
        #pragma unroll
        for (int ic = 0; ic < 4; ++ic) {
            float p[4][4];
            const float* base = sm + ic*484 + y0*22 + x0;
            #pragma unroll
            for (int u = 0; u < 4; ++u)
                #pragma unroll
                for (int v = 0; v < 4; ++v)
                    p[u][v] = base[u*22 + v];
            const float* wp = ws + (c*4 + ic)*9;
            #pragma unroll
            for (int ky = 0; ky < 3; ++ky) {
                #pragma unroll
                for (int kx = 0; kx < 3; ++kx) {
                    const float wv = wp[ky*3 + kx];
                    a0 = fmaf(wv, p[ky  ][kx  ], a0);
                    a1 = fmaf(wv, p[ky  ][kx+1], a1);
                    a2 = fmaf(wv, p[ky+1][kx  ], a2);
                    a3 = fmaf(wv, p[ky+1][kx+1], a3);
                }
            }
        }
        float m = fmaxf(fmaxf(a0, a1), fmaxf(a2, a3));
        out[(size_t)b*200 + tid] = fmaxf(m, 0.f);
    }
}

// ---------------------------------------------------------------------------
// Generic GEMM: C[m][n] = relu(sum_k A[m][k]*W[k][n] + b[n]), M-tile 128,
// N-tile NT=16*NW, 256 threads, micro 8 x NW, K chunked by 32 in LDS.
// FLATW: n -> (r=n/140, h=n%140), W at r*28000 + k*140 + h (head L1 flatten).
// FUSE4: L3+L4 fusion — relu'd tile to LDS, then 42->4 per-row GEMM to out.
// ---------------------------------------------------------------------------
template<int NW, bool FLATW, bool FUSE4>
__global__ __launch_bounds__(256, 4) void gemm_k(
        const float* __restrict__ A, long a_rstride, int lda,
        const float* __restrict__ W, long w_rstride,
        const float* __restrict__ bias, int b_rstride,
        float* __restrict__ C, long c_rstride, int ldc,
        int M, int N, int K, int do_relu,
        const float* __restrict__ W4g, const float* __restrict__ b4g) {
    constexpr int NT = NW * 16;
    constexpr int MAIN = 32*132 + 32*NT;
    constexpr int PSZ = FUSE4 ? (128*49 + 172 > MAIN ? 128*49 + 172 : MAIN) : MAIN;
    __shared__ float pool[PSZ];
    float (*As)[132] = (float(*)[132])pool;
    float* Ws = pool + 32*132;             // [32][NT]

    const int r  = blockIdx.z;
    const int m0 = blockIdx.y * 128;
    const int n0 = blockIdx.x * NT;
    const float* Ab = A + (long)r * a_rstride;
    const float* Wb = W + (long)r * w_rstride;
    const float* bb = bias + (long)r * b_rstride;
    const int tid = threadIdx.x;
    const int ti = tid >> 4, tj = tid & 15;

    if (FUSE4) {   // stage W4 [42][4] + b4 [4] beyond the P region overlap
        if (tid < 168) pool[128*49 + tid] = W4g[(long)r*168 + tid];
        if (tid < 4)   pool[128*49 + 168 + tid] = b4g[(long)r*4 + tid];
    }

    float acc[8][NW];
    #pragma unroll
    for (int i = 0; i < 8; ++i)
        #pragma unroll
        for (int j = 0; j < NW; ++j) acc[i][j] = 0.f;

    for (int k0 = 0; k0 < K; k0 += 32) {
        // ---- stage A (128 x 32), transposed into As[k][m] ----
        #pragma unroll
        for (int i = 0; i < 4; ++i) {
            const int f = tid + i*256;
            const int m = f >> 3, kg = f & 7;
            const int kk = kg*4;
            float4 v = make_float4(0.f, 0.f, 0.f, 0.f);
            if (k0 + kk < K)   // K always multiple of 4 -> all-or-nothing
                v = *(const float4*)(Ab + (long)(m0 + m)*lda + k0 + kk);
            As[kk+0][m] = v.x;
            As[kk+1][m] = v.y;
            As[kk+2][m] = v.z;
            As[kk+3][m] = v.w;
        }
        // ---- stage W (32 x NT), zero-fill pad cols ----
        for (int f = tid; f < NT*8; f += 256) {
            const int kk = f / (NT/4);
            const int cg = f - kk*(NT/4);
            const int n  = n0 + cg*4;
            float4 v = make_float4(0.f, 0.f, 0.f, 0.f);
            if (k0 + kk < K) {
                if (FLATW) {
                    if (n + 3 < N) {   // 140%4==0: groups never cross r
                        const int rn = n / 140;
                        const int h  = n - rn*140;
                        v = *(const float4*)(W + (long)rn*28000 +
                                             (long)(k0+kk)*140 + h);
                    }
                } else if (NW == 3) {  // L3: row stride 42 floats -> 8B align only
                    const float* wp = Wb + (long)(k0+kk)*N;
                    if (n+0 < N) v.x = wp[n+0];
                    if (n+1 < N) v.y = wp[n+1];
                    if (n+2 < N) v.z = wp[n+2];
                    if (n+3 < N) v.w = wp[n+3];
                } else {
                    const float* wp = Wb + (long)(k0+kk)*N;
                    if (n + 3 < N) v = *(const float4*)(wp + n);
                    else {
                        if (n+0 < N) v.x = wp[n+0];
                        if (n+1 < N) v.y = wp[n+1];
                        if (n+2 < N) v.z = wp[n+2];
                    }
                }
            }
            *(float4*)&Ws[kk*NT + cg*4] = v;
        }
        __syncthreads();
        // ---- FMA inner loop ----
        #pragma unroll
        for (int kk = 0; kk < 32; ++kk) {
            float a[8], wv[NW];
            *(float4*)&a[0] = *(const float4*)&As[kk][ti*8];
            *(float4*)&a[4] = *(const float4*)&As[kk][ti*8 + 4];
            if (NW == 4) {
                *(float4*)&wv[0] = *(const float4*)&Ws[kk*NT + tj*4];
            } else if (NW == 6) {
                *(float2*)&wv[0] = *(const float2*)&Ws[kk*NT + tj*6 + 0];
                *(float2*)&wv[2] = *(const float2*)&Ws[kk*NT + tj*6 + 2];
                *(float2*)&wv[4] = *(const float2*)&Ws[kk*NT + tj*6 + 4];
            } else {
                #pragma unroll
                for (int j = 0; j < NW; ++j) wv[j] = Ws[kk*NT + tj*NW + j];
            }
            #pragma unroll
            for (int i = 0; i < 8; ++i)
                #pragma unroll
                for (int j = 0; j < NW; ++j)
                    acc[i][j] = fmaf(a[i], wv[j], acc[i][j]);
        }
        __syncthreads();
    }

    if (!FUSE4) {
        if (NW == 4) {
            const int n = n0 + tj*4;
            if (n + 3 < N) {
                float4 bv = *(const float4*)&bb[n];
                #pragma unroll
                for (int i = 0; i < 8; ++i) {
                    const long m = m0 + ti*8 + i;
                    float4 v;
                    v.x = acc[i][0] + bv.x; v.y = acc[i][1] + bv.y;
                    v.z = acc[i][2] + bv.z; v.w = acc[i][3] + bv.w;
                    if (do_relu) {
                        v.x = fmaxf(v.x, 0.f); v.y = fmaxf(v.y, 0.f);
                        v.z = fmaxf(v.z, 0.f); v.w = fmaxf(v.w, 0.f);
                    }
                    *(float4*)(C + (long)r*c_rstride + m*(long)ldc + n) = v;
                }
            } else {
                #pragma unroll
                for (int i = 0; i < 8; ++i) {
                    const long m = m0 + ti*8 + i;
                    #pragma unroll
                    for (int j = 0; j < 4; ++j) {
                        const int nn = n + j;
                        if (nn < N) {
                            float v = acc[i][j] + bb[nn];
                            if (do_relu) v = fmaxf(v, 0.f);
                            C[(long)r*c_rstride + m*(long)ldc + nn] = v;
                        }
                    }
                }
            }
        } else {
            #pragma unroll
            for (int i = 0; i < 8; ++i) {
                const long m = m0 + ti*8 + i;
                #pragma unroll
                for (int j = 0; j < NW; ++j) {
                    const int n = n0 + tj*NW + j;
                    if (n < N) {
                        float v = acc[i][j] + bb[n];
                        if (do_relu) v = fmaxf(v, 0.f);
                        C[(long)r*c_rstride + m*(long)ldc + n] = v;
                    }
                }
            }
        }
    } else {
        // L3 epilogue: relu'd tile -> P (LDS, stride 49), then fused L4.
        float* P  = pool;                   // [128][49] (reuses As/Ws space)
        float* W4 = pool + 128*49;          // [42][4]
        float* b4 = pool + 128*49 + 168;    // [4]
        #pragma unroll
        for (int i = 0; i < 8; ++i) {
            const int ml = ti*8 + i;
            #pragma unroll
            for (int j = 0; j < NW; ++j) {
                const int n = tj*NW + j;    // n0 == 0 for FUSE4 grid
                if (n < N) {
                    float v = acc[i][j] + bb[n];
                    if (do_relu) v = fmaxf(v, 0.f);
                    P[ml*49 + n] = v;
                }
            }
        }
        __syncthreads();
        if (tid < 128) {
            float o0 = b4[0], o1 = b4[1], o2 = b4[2], o3 = b4[3];
            #pragma unroll
            for (int d = 0; d < 42; ++d) {
                const float pv = P[tid*49 + d];
                o0 = fmaf(pv, W4[d*4+0], o0);
                o1 = fmaf(pv, W4[d*4+1], o1);
                o2 = fmaf(pv, W4[d*4+2], o2);
                o3 = fmaf(pv, W4[d*4+3], o3);
            }
            float4 ov = make_float4(o0, o1, o2, o3);
            *(float4*)(C + (size_t)(m0 + tid)*400 + r*4) = ov;
        }
    }
}

extern "C" void kernel_launch(void* const* d_in, const int* in_sizes, int n_in,
                              void* d_out, int out_size, void* d_ws, size_t ws_size,
                              hipStream_t stream) {
    const float* x    = (const float*)d_in[0];
    const float* c1w  = (const float*)d_in[1];
    const float* c1b  = (const float*)d_in[2];
    const float* c2w  = (const float*)d_in[3];
    const float* c2b  = (const float*)d_in[4];
    const float* c3w  = (const float*)d_in[5];
    const float* c3b  = (const float*)d_in[6];
    const float* fc1w = (const float*)d_in[7];
    const float* fc1b = (const float*)d_in[8];
    const float* fc2w = (const float*)d_in[9];
    const float* fc2b = (const float*)d_in[10];
    const float* h1w  = (const float*)d_in[11];
    const float* h1b  = (const float*)d_in[12];
    const float* h2w  = (const float*)d_in[13];
    const float* h2b  = (const float*)d_in[14];
    const float* h3w  = (const float*)d_in[15];
    const float* h3b  = (const float*)d_in[16];
    const float* h4w  = (const float*)d_in[17];
    const float* h4b  = (const float*)d_in[18];
    float* out = (float*)d_out;

    // workspace regions (aliased by liveness):
    //  region0 (59.0MB): t1[B,6,49,49] -> G1[B,14000] (57.3MB)
    //  region1 (34.4MB): t2[B,4,22,22] (7.9MB) -> G2[B,8400] (34.4MB)
    //  region2 (0.8MB):  t3[B,200] -> f2[B,200]
    //  region3 (1.6MB):  f1[B,400]
    char* ws = (char*)d_ws;
    const size_t off1 = (size_t)NB*6*2401*sizeof(float);
    const size_t off2 = off1 + (size_t)NB*8400*sizeof(float);
    const size_t off3 = off2 + (size_t)NB*200*sizeof(float);
    float* t1 = (float*)(ws);
    float* t2 = (float*)(ws + off1);
    float* t3 = (float*)(ws + off2);
    float* f1 = (float*)(ws + off3);
    float* f2 = t3;
    float* G1 = t1;   // [B][14000], col (r,h) at r*140+h
    float* G2 = t2;   // [B][8400],  col (r,d) at r*84+d

    conv1_k<<<NB, 256, 0, stream>>>(x, c1w, c1b, t1);
    conv2_k<<<NB*4, 256, 0, stream>>>(t1, c2w, c2b, t2);
    conv3_k<<<NB, 256, 0, stream>>>(t2, c3w, c3b, t3);

    // fc1: [1024,200] x [200,400]
    gemm_k<4,false,false><<<dim3(7, 8, 1), 256, 0, stream>>>(
        t3, 0, 200, fc1w, 0, fc1b, 0, f1, 0, 400, NB, 400, 200, 1,
        nullptr, nullptr);
    // fc2: [1024,400] x [400,200]
    gemm_k<4,false,false><<<dim3(4, 8, 1), 256, 0, stream>>>(
        f1, 0, 400, fc2w, 0, fc2b, 0, f2, 0, 200, NB, 200, 400, 1,
        nullptr, nullptr);
    // head L1 flattened: [1024,200] x [200,14000] -> G1
    gemm_k<4,true,false><<<dim3(219, 8, 1), 256, 0, stream>>>(
        f2, 0, 200, h1w, 0, h1b, 0, G1, 0, 14000, NB, 14000, 200, 1,
        nullptr, nullptr);
    // head L2 per-r: A = G1[:, r*140 : r*140+140], N=84 (NT=96 zero-padded)
    gemm_k<6,false,false><<<dim3(1, 8, NR), 256, 0, stream>>>(
        G1, 140, 14000, h2w, 11760, h2b, 84, G2, 84, 8400, NB, 84, 140, 1,
        nullptr, nullptr);
    // head L3+L4 fused: A = G2[:, r*84 : r*84+84], N=42 (NT=48), writes out
    gemm_k<3,false,true><<<dim3(1, 8, NR), 256, 0, stream>>>(
        G2, 84, 8400, h3w, 3528, h3b, 42, out, 0, 0, NB, 42, 84, 1,
        h4w, h4b);
    (void)in_sizes; (void)n_in; (void)out_size; (void)ws_size;
}

// Round 4
// 262.509 us; speedup vs baseline: 1.6348x; 1.3517x over previous
//
#include <hip/hip_runtime.h>

#define NB 1024
#define NR 100

typedef _Float16 half_t;
typedef half_t f16x8 __attribute__((ext_vector_type(8)));
typedef float f32x4 __attribute__((ext_vector_type(4)));

// fragment k-map used CONSISTENTLY for all A and B operands:
// k_local = g*4 + (j&3) + 16*(j>>2)   (g = lane>>4, j = elem 0..7)
__device__ __forceinline__ int kmap2(int g, int j) {
    return g*4 + (j & 3) + ((j >> 2) << 4);
}

// ---------------------------------------------------------------------------
// conv1: x[B,1,98,98] -> out[B,6,49,49]   (conv 3x3 pad1 + relu + maxpool2)
// ---------------------------------------------------------------------------
__global__ __launch_bounds__(256) void conv1_k(const float* __restrict__ x,
        const float* __restrict__ w, const float* __restrict__ bias,
        float* __restrict__ out) {
    __shared__ float img[98*98];
    __shared__ float ws[54];
    __shared__ float bs[6];
    const int b = blockIdx.x;
    const int tid = threadIdx.x;
    const float* xb = x + (size_t)b * 9604;
    for (int i = tid; i < 2401; i += 256)
        ((float4*)img)[i] = ((const float4*)xb)[i];
    if (tid < 54) ws[tid] = w[tid];
    if (tid < 6) bs[tid] = bias[tid];
    __syncthreads();
    for (int pos = tid; pos < 2401; pos += 256) {
        const int py = pos / 49, px = pos % 49;
        const int y0 = 2*py - 1, x0 = 2*px - 1;
        float p[4][4];
        #pragma unroll
        for (int dy = 0; dy < 4; ++dy) {
            const int iy = y0 + dy;
            #pragma unroll
            for (int dx = 0; dx < 4; ++dx) {
                const int ix = x0 + dx;
                p[dy][dx] = (iy >= 0 && iy < 98 && ix >= 0 && ix < 98)
                            ? img[iy*98 + ix] : 0.f;
            }
        }
        #pragma unroll
        for (int c = 0; c < 6; ++c) {
            float v0 = bs[c], v1 = bs[c], v2 = bs[c], v3 = bs[c];
            #pragma unroll
            for (int ky = 0; ky < 3; ++ky) {
                #pragma unroll
                for (int kx = 0; kx < 3; ++kx) {
                    const float wv = ws[c*9 + ky*3 + kx];
                    v0 = fmaf(wv, p[ky  ][kx  ], v0);
                    v1 = fmaf(wv, p[ky  ][kx+1], v1);
                    v2 = fmaf(wv, p[ky+1][kx  ], v2);
                    v3 = fmaf(wv, p[ky+1][kx+1], v3);
                }
            }
            float m = fmaxf(fmaxf(v0, v1), fmaxf(v2, v3));
            out[((size_t)b*6 + c)*2401 + pos] = fmaxf(m, 0.f);
        }
    }
}

// ---------------------------------------------------------------------------
// conv2: in[B,6,49,49] -> out[B,4,22,22]  (conv 6x6 VALID + relu + maxpool2)
// ---------------------------------------------------------------------------
__global__ __launch_bounds__(256, 4) void conv2_k(const float* __restrict__ in,
        const float* __restrict__ w, const float* __restrict__ bias,
        float* __restrict__ out) {
    __shared__ float smc[6*27*28];
    __shared__ float ws[864];
    __shared__ float bs[4];
    const int blk = blockIdx.x;
    const int b  = blk >> 2;
    const int qy = (blk >> 1) & 1, qx = blk & 1;
    const int r0 = qy*22, c0 = qx*22;
    const int tid = threadIdx.x;
    const float* src = in + (size_t)b * 14406;
    for (int idx = tid; idx < 6*27*27; idx += 256) {
        const int ic  = idx / 729;
        const int rem = idx - ic*729;
        const int rr  = rem / 27;
        const int cc  = rem - rr*27;
        smc[ic*756 + rr*28 + cc] = src[ic*2401 + (r0+rr)*49 + c0 + cc];
    }
    for (int i = tid; i < 864; i += 256) ws[i] = w[i];
    if (tid < 4) bs[tid] = bias[tid];
    __syncthreads();
    if (tid < 242) {
        const int ocg = tid / 121;
        const int p   = tid - ocg*121;
        const int py  = p / 11, px = p - py*11;
        const int y0  = 2*py, x0 = 2*px;
        float acc[2][4];
        #pragma unroll
        for (int o = 0; o < 2; ++o) {
            const float bv = bs[ocg*2 + o];
            acc[o][0] = acc[o][1] = acc[o][2] = acc[o][3] = bv;
        }
        #pragma unroll
        for (int ic = 0; ic < 6; ++ic) {
            float pt[7][7];
            const float* basep = smc + ic*756 + y0*28 + x0;
            #pragma unroll
            for (int u = 0; u < 7; ++u) {
                const float* rb = basep + u*28;
                *(float2*)&pt[u][0] = *(const float2*)&rb[0];
                *(float2*)&pt[u][2] = *(const float2*)&rb[2];
                *(float2*)&pt[u][4] = *(const float2*)&rb[4];
                pt[u][6] = rb[6];
            }
            #pragma unroll
            for (int o = 0; o < 2; ++o) {
                const float* wp = ws + ((ocg*2 + o)*6 + ic)*36;
                #pragma unroll
                for (int ky = 0; ky < 6; ++ky) {
                    #pragma unroll
                    for (int kx = 0; kx < 6; ++kx) {
                        const float wv = wp[ky*6 + kx];
                        acc[o][0] = fmaf(wv, pt[ky  ][kx  ], acc[o][0]);
                        acc[o][1] = fmaf(wv, pt[ky  ][kx+1], acc[o][1]);
                        acc[o][2] = fmaf(wv, pt[ky+1][kx  ], acc[o][2]);
                        acc[o][3] = fmaf(wv, pt[ky+1][kx+1], acc[o][3]);
                    }
                }
            }
        }
        const int PY = qy*11 + py, PX = qx*11 + px;
        #pragma unroll
        for (int o = 0; o < 2; ++o) {
            const int oc = ocg*2 + o;
            float m = fmaxf(fmaxf(acc[o][0], acc[o][1]),
                            fmaxf(acc[o][2], acc[o][3]));
            out[(((size_t)b*4 + oc)*22 + PY)*22 + PX] = fmaxf(m, 0.f);
        }
    }
}

// ---------------------------------------------------------------------------
// conv3: in[B,4,22,22] -> out[B,200]
// ---------------------------------------------------------------------------
__global__ __launch_bounds__(256) void conv3_k(const float* __restrict__ in,
        const float* __restrict__ w, const float* __restrict__ bias,
        float* __restrict__ out) {
    __shared__ float sm[1936];
    __shared__ float ws[72];
    __shared__ float bs[2];
    const int b = blockIdx.x;
    const int tid = threadIdx.x;
    const float* src = in + (size_t)b * 1936;
    for (int i = tid; i < 484; i += 256)
        ((float4*)sm)[i] = ((const float4*)src)[i];
    if (tid < 72) ws[tid] = w[tid];
    if (tid < 2) bs[tid] = bias[tid];
    __syncthreads();
    if (tid < 200) {
        const int c = tid / 100;
        const int rem = tid % 100;
        const int py = rem / 10, px = rem % 10;
        const int y0 = 2*py, x0 = 2*px;
        float a0, a1, a2, a3;
        a0 = a1 = a2 = a3 = bs[c];
        #pragma unroll
        for (int ic = 0; ic < 4; ++ic) {
            float p[4][4];
            const float* base = sm + ic*484 + y0*22 + x0;
            #pragma unroll
            for (int u = 0; u < 4; ++u)
                #pragma unroll
                for (int v = 0; v < 4; ++v)
                    p[u][v] = base[u*22 + v];
            const float* wp = ws + (c*4 + ic)*9;
            #pragma unroll
            for (int ky = 0; ky < 3; ++ky) {
                #pragma unroll
                for (int kx = 0; kx < 3; ++kx) {
                    const float wv = wp[ky*3 + kx];
                    a0 = fmaf(wv, p[ky  ][kx  ], a0);
                    a1 = fmaf(wv, p[ky  ][kx+1], a1);
                    a2 = fmaf(wv, p[ky+1][kx  ], a2);
                    a3 = fmaf(wv, p[ky+1][kx+1], a3);
                }
            }
        }
        float m = fmaxf(fmaxf(a0, a1), fmaxf(a2, a3));
        out[(size_t)b*200 + tid] = fmaxf(m, 0.f);
    }
}

// ---------------------------------------------------------------------------
// f32 GEMM (fc1 / fc2), 128x64 tile. G0OUT: write packed f16 hi/lo fragment
// planes (B-fragment layout for the head kernel) instead of f32 C.
// ---------------------------------------------------------------------------
template<bool G0OUT>
__global__ __launch_bounds__(256, 4) void gemm_k(
        const float* __restrict__ A, int lda,
        const float* __restrict__ W, const float* __restrict__ bias,
        float* __restrict__ C, int ldc,
        int M, int N, int K,
        half_t* __restrict__ g0h, half_t* __restrict__ g0l) {
    __shared__ float As[32][132];
    __shared__ float Ws[32][64];
    const int m0 = blockIdx.y * 128;
    const int n0 = blockIdx.x * 64;
    const int tid = threadIdx.x;
    const int ti = tid >> 4, tj = tid & 15;
    float acc[8][4];
    #pragma unroll
    for (int i = 0; i < 8; ++i)
        #pragma unroll
        for (int j = 0; j < 4; ++j) acc[i][j] = 0.f;

    for (int k0 = 0; k0 < K; k0 += 32) {
        #pragma unroll
        for (int i = 0; i < 4; ++i) {
            const int f = tid + i*256;
            const int m = f >> 3, kg = f & 7;
            const int kk = kg*4;
            float4 v = make_float4(0.f, 0.f, 0.f, 0.f);
            if (k0 + kk < K)
                v = *(const float4*)(A + (long)(m0 + m)*lda + k0 + kk);
            As[kk+0][m] = v.x;
            As[kk+1][m] = v.y;
            As[kk+2][m] = v.z;
            As[kk+3][m] = v.w;
        }
        #pragma unroll
        for (int i = 0; i < 2; ++i) {
            const int f = tid + i*256;
            const int kk = f >> 4, cg = f & 15;
            const int n = n0 + cg*4;
            float4 v = make_float4(0.f, 0.f, 0.f, 0.f);
            if (k0 + kk < K) {
                const float* wp = W + (long)(k0 + kk)*N;
                if (n + 3 < N) v = *(const float4*)(wp + n);
                else {
                    if (n+0 < N) v.x = wp[n+0];
                    if (n+1 < N) v.y = wp[n+1];
                    if (n+2 < N) v.z = wp[n+2];
                }
            }
            *(float4*)&Ws[kk][cg*4] = v;
        }
        __syncthreads();
        #pragma unroll
        for (int kk = 0; kk < 32; ++kk) {
            float a[8], wv[4];
            *(float4*)&a[0] = *(const float4*)&As[kk][ti*8];
            *(float4*)&a[4] = *(const float4*)&As[kk][ti*8 + 4];
            *(float4*)&wv[0] = *(const float4*)&Ws[kk][tj*4];
            #pragma unroll
            for (int i = 0; i < 8; ++i)
                #pragma unroll
                for (int j = 0; j < 4; ++j)
                    acc[i][j] = fmaf(a[i], wv[j], acc[i][j]);
        }
        __syncthreads();
    }

    const int nb = n0 + tj*4;
    float bv[4] = {0.f, 0.f, 0.f, 0.f};
    #pragma unroll
    for (int e = 0; e < 4; ++e) if (nb + e < N) bv[e] = bias[nb + e];

    if (!G0OUT) {
        #pragma unroll
        for (int i = 0; i < 8; ++i) {
            const long m = m0 + ti*8 + i;
            if (nb + 3 < N) {
                float4 v;
                v.x = fmaxf(acc[i][0] + bv[0], 0.f);
                v.y = fmaxf(acc[i][1] + bv[1], 0.f);
                v.z = fmaxf(acc[i][2] + bv[2], 0.f);
                v.w = fmaxf(acc[i][3] + bv[3], 0.f);
                *(float4*)(C + m*(long)ldc + nb) = v;
            } else {
                #pragma unroll
                for (int j = 0; j < 4; ++j)
                    if (nb + j < N)
                        C[m*(long)ldc + nb + j] = fmaxf(acc[i][j] + bv[j], 0.f);
            }
        }
    } else {
        // write packed f16 hi/lo planes in B-fragment order:
        // idx = ((mb*7 + kc)*64 + (g<<4 | m&15))*8 + j,  k = kc*32 + kmap2(g,j)
        #pragma unroll
        for (int i = 0; i < 8; ++i) {
            const int m = m0 + ti*8 + i;
            #pragma unroll
            for (int j = 0; j < 4; ++j) {
                const int k = nb + j;
                if (k < N) {
                    const float v = fmaxf(acc[i][j] + bv[j], 0.f);
                    const half_t hi = (half_t)v;
                    const half_t lo = (half_t)(v - (float)hi);
                    const int kc = k >> 5, klo = k & 31;
                    const int h = klo >> 4, rm = klo & 15;
                    const int gg = rm >> 2, rr = rm & 3;
                    const size_t idx =
                        ((size_t)((m >> 4)*7 + kc)*64 + (gg << 4) + (m & 15))*8
                        + h*4 + rr;
                    g0h[idx] = hi;
                    g0l[idx] = lo;
                }
            }
        }
    }
}

// ---------------------------------------------------------------------------
// wsplit: all 4 head weight arrays f32 -> fragment-ordered f16 hi/lo planes.
// A-operand (W^T) fragment: value(l, j) = W[k = kc*32+kmap2(g,j)][n = nf*16+c]
// stored at ((r*KC + kc)*NF + nf)*512 + l*8 + j.  Zero-padded beyond K/N.
// grid: x = chunk id 0..16 (L1:0-6, L2:7-11, L3:12-14, L4:15-16), y = r.
// ---------------------------------------------------------------------------
__global__ __launch_bounds__(256) void wsplit_k(
        const float* __restrict__ w1, const float* __restrict__ w2,
        const float* __restrict__ w3, const float* __restrict__ w4,
        half_t* __restrict__ f1h, half_t* __restrict__ f1l,
        half_t* __restrict__ f2h, half_t* __restrict__ f2l,
        half_t* __restrict__ f3h, half_t* __restrict__ f3l,
        half_t* __restrict__ f4h, half_t* __restrict__ f4l) {
    __shared__ float lds[32*140];
    const int cx = blockIdx.x, r = blockIdx.y, tid = threadIdx.x;
    int K, N, KC, NF, kc;
    const float* src;
    half_t *dh, *dl;
    if (cx < 7)       { K=200; N=140; KC=7; NF=9; kc=cx;    src=w1; dh=f1h; dl=f1l; }
    else if (cx < 12) { K=140; N=84;  KC=5; NF=6; kc=cx-7;  src=w2; dh=f2h; dl=f2l; }
    else if (cx < 15) { K=84;  N=42;  KC=3; NF=3; kc=cx-12; src=w3; dh=f3h; dl=f3l; }
    else              { K=42;  N=4;   KC=2; NF=1; kc=cx-15; src=w4; dh=f4h; dl=f4l; }
    const float* sb = src + (size_t)r * K * N;
    for (int i = tid; i < 32*N; i += 256) {
        const int kk = i / N, n = i - kk*N;
        const int kg = kc*32 + kk;
        lds[kk*N + n] = (kg < K) ? sb[(size_t)kg*N + n] : 0.f;
    }
    __syncthreads();
    const size_t base = ((size_t)r*KC + kc)*NF*512;
    for (int e = tid; e < NF*512; e += 256) {
        const int nf = e >> 9, rem = e & 511;
        const int l = rem >> 3, j = rem & 7;
        const int g = l >> 4, c = l & 15;
        const int kl = kmap2(g, j);
        const int n = nf*16 + c;
        const float v = (n < N) ? lds[kl*N + n] : 0.f;
        const half_t hi = (half_t)v;
        const half_t lo = (half_t)(v - (float)hi);
        dh[base + (size_t)nf*512 + rem] = hi;
        dl[base + (size_t)nf*512 + rem] = lo;
    }
}

// ---------------------------------------------------------------------------
// head_k: entire per-radical chain 200->140->84->42->4 fused, split-f16 MFMA.
// Swapped form: out^T = W^T * in^T, so each layer's C/D accumulator IS the
// next layer's B-fragment (after bias+relu+split, all in registers).
// grid (8 m-tiles, 100 r); 4 waves x 2 m-blocks of 16 batch rows.
// ---------------------------------------------------------------------------
#define MFMA(a, b, c) __builtin_amdgcn_mfma_f32_16x16x32_f16(a, b, c, 0, 0, 0)

__global__ __launch_bounds__(256, 2) void head_k(
        const half_t* __restrict__ g0h, const half_t* __restrict__ g0l,
        const half_t* __restrict__ w1h, const half_t* __restrict__ w1l,
        const half_t* __restrict__ w2h, const half_t* __restrict__ w2l,
        const half_t* __restrict__ w3h, const half_t* __restrict__ w3l,
        const half_t* __restrict__ w4h, const half_t* __restrict__ w4l,
        const float* __restrict__ b1, const float* __restrict__ b2,
        const float* __restrict__ b3, const float* __restrict__ b4,
        float* __restrict__ out) {
    __shared__ float bl[270];
    const int mt = blockIdx.x;   // 0..7
    const int r  = blockIdx.y;   // 0..99
    const int tid = threadIdx.x;
    if (tid < 140) bl[tid]       = b1[(size_t)r*140 + tid];
    if (tid < 84)  bl[140 + tid] = b2[(size_t)r*84  + tid];
    if (tid < 42)  bl[224 + tid] = b3[(size_t)r*42  + tid];
    if (tid < 4)   bl[266 + tid] = b4[(size_t)r*4   + tid];
    __syncthreads();
    const int w = tid >> 6, l = tid & 63;
    const int g4 = ((l >> 4) & 3) * 4;
    const int mb0 = mt*8 + w*2;      // global m-block (16 batch rows each)

    // ===================== L1: K=200 (7 chunks), N=140 (9 frags) ==========
    f32x4 a1[2][9] = {};
    for (int kc = 0; kc < 7; ++kc) {
        f16x8 bh[2], blo[2];
        #pragma unroll
        for (int mb = 0; mb < 2; ++mb) {
            const size_t bo = ((size_t)(mb0 + mb)*7 + kc)*512 + (size_t)l*8;
            bh[mb]  = *(const f16x8*)(g0h + bo);
            blo[mb] = *(const f16x8*)(g0l + bo);
        }
        #pragma unroll
        for (int nf = 0; nf < 9; ++nf) {
            const size_t wo = (((size_t)r*7 + kc)*9 + nf)*512 + (size_t)l*8;
            const f16x8 wh = *(const f16x8*)(w1h + wo);
            const f16x8 wl = *(const f16x8*)(w1l + wo);
            #pragma unroll
            for (int mb = 0; mb < 2; ++mb) {
                a1[mb][nf] = MFMA(wh, bh[mb],  a1[mb][nf]);
                a1[mb][nf] = MFMA(wh, blo[mb], a1[mb][nf]);
                a1[mb][nf] = MFMA(wl, bh[mb],  a1[mb][nf]);
            }
        }
    }
    // ---- convert a1 -> L2 B-fragments (bias+relu+split), N1=140 ----
    f16x8 b2h[2][5], b2l[2][5];
    #pragma unroll
    for (int kc = 0; kc < 5; ++kc)
        #pragma unroll
        for (int h = 0; h < 2; ++h) {
            const int nf = kc*2 + h;
            #pragma unroll
            for (int mb = 0; mb < 2; ++mb)
                #pragma unroll
                for (int rr = 0; rr < 4; ++rr) {
                    float v = 0.f;
                    if (nf < 9) {
                        const int n = nf*16 + g4 + rr;
                        v = (n < 140) ? fmaxf(a1[mb][nf][rr] + bl[n], 0.f) : 0.f;
                    }
                    const half_t hi = (half_t)v;
                    const half_t lo = (half_t)(v - (float)hi);
                    b2h[mb][kc][h*4+rr] = hi;
                    b2l[mb][kc][h*4+rr] = lo;
                }
        }
    // ===================== L2: K=140 (5 chunks), N=84 (6 frags) ===========
    f32x4 a2[2][6] = {};
    #pragma unroll
    for (int kc = 0; kc < 5; ++kc)
        #pragma unroll
        for (int nf = 0; nf < 6; ++nf) {
            const size_t wo = (((size_t)r*5 + kc)*6 + nf)*512 + (size_t)l*8;
            const f16x8 wh = *(const f16x8*)(w2h + wo);
            const f16x8 wl = *(const f16x8*)(w2l + wo);
            #pragma unroll
            for (int mb = 0; mb < 2; ++mb) {
                a2[mb][nf] = MFMA(wh, b2h[mb][kc], a2[mb][nf]);
                a2[mb][nf] = MFMA(wh, b2l[mb][kc], a2[mb][nf]);
                a2[mb][nf] = MFMA(wl, b2h[mb][kc], a2[mb][nf]);
            }
        }
    // ---- convert a2 -> L3 B-fragments, N2=84 ----
    f16x8 b3h[2][3], b3l[2][3];
    #pragma unroll
    for (int kc = 0; kc < 3; ++kc)
        #pragma unroll
        for (int h = 0; h < 2; ++h) {
            const int nf = kc*2 + h;
            #pragma unroll
            for (int mb = 0; mb < 2; ++mb)
                #pragma unroll
                for (int rr = 0; rr < 4; ++rr) {
                    float v = 0.f;
                    if (nf < 6) {
                        const int n = nf*16 + g4 + rr;
                        v = (n < 84) ? fmaxf(a2[mb][nf][rr] + bl[140 + n], 0.f) : 0.f;
                    }
                    const half_t hi = (half_t)v;
                    const half_t lo = (half_t)(v - (float)hi);
                    b3h[mb][kc][h*4+rr] = hi;
                    b3l[mb][kc][h*4+rr] = lo;
                }
        }
    // ===================== L3: K=84 (3 chunks), N=42 (3 frags) ============
    f32x4 a3[2][3] = {};
    #pragma unroll
    for (int kc = 0; kc < 3; ++kc)
        #pragma unroll
        for (int nf = 0; nf < 3; ++nf) {
            const size_t wo = (((size_t)r*3 + kc)*3 + nf)*512 + (size_t)l*8;
            const f16x8 wh = *(const f16x8*)(w3h + wo);
            const f16x8 wl = *(const f16x8*)(w3l + wo);
            #pragma unroll
            for (int mb = 0; mb < 2; ++mb) {
                a3[mb][nf] = MFMA(wh, b3h[mb][kc], a3[mb][nf]);
                a3[mb][nf] = MFMA(wh, b3l[mb][kc], a3[mb][nf]);
                a3[mb][nf] = MFMA(wl, b3h[mb][kc], a3[mb][nf]);
            }
        }
    // ---- convert a3 -> L4 B-fragments, N3=42 ----
    f16x8 b4h[2][2], b4l[2][2];
    #pragma unroll
    for (int kc = 0; kc < 2; ++kc)
        #pragma unroll
        for (int h = 0; h < 2; ++h) {
            const int nf = kc*2 + h;
            #pragma unroll
            for (int mb = 0; mb < 2; ++mb)
                #pragma unroll
                for (int rr = 0; rr < 4; ++rr) {
                    float v = 0.f;
                    if (nf < 3) {
                        const int n = nf*16 + g4 + rr;
                        v = (n < 42) ? fmaxf(a3[mb][nf][rr] + bl[224 + n], 0.f) : 0.f;
                    }
                    const half_t hi = (half_t)v;
                    const half_t lo = (half_t)(v - (float)hi);
                    b4h[mb][kc][h*4+rr] = hi;
                    b4l[mb][kc][h*4+rr] = lo;
                }
        }
    // ===================== L4: K=42 (2 chunks), N=4 (1 frag), no relu =====
    f32x4 a4[2] = {};
    #pragma unroll
    for (int kc = 0; kc < 2; ++kc) {
        const size_t wo = ((size_t)r*2 + kc)*512 + (size_t)l*8;
        const f16x8 wh = *(const f16x8*)(w4h + wo);
        const f16x8 wl = *(const f16x8*)(w4l + wo);
        #pragma unroll
        for (int mb = 0; mb < 2; ++mb) {
            a4[mb] = MFMA(wh, b4h[mb][kc], a4[mb]);
            a4[mb] = MFMA(wh, b4l[mb][kc], a4[mb]);
            a4[mb] = MFMA(wl, b4h[mb][kc], a4[mb]);
        }
    }
    // epilogue: rows 0..3 live in lane group g==0 (row = g*4+reg)
    if ((l >> 4) == 0) {
        #pragma unroll
        for (int mb = 0; mb < 2; ++mb) {
            const int b = (mb0 + mb)*16 + (l & 15);
            float4 o;
            o.x = a4[mb][0] + bl[266];
            o.y = a4[mb][1] + bl[267];
            o.z = a4[mb][2] + bl[268];
            o.w = a4[mb][3] + bl[269];
            *(float4*)(out + (size_t)b*400 + r*4) = o;
        }
    }
}

extern "C" void kernel_launch(void* const* d_in, const int* in_sizes, int n_in,
                              void* d_out, int out_size, void* d_ws, size_t ws_size,
                              hipStream_t stream) {
    const float* x    = (const float*)d_in[0];
    const float* c1w  = (const float*)d_in[1];
    const float* c1b  = (const float*)d_in[2];
    const float* c2w  = (const float*)d_in[3];
    const float* c2b  = (const float*)d_in[4];
    const float* c3w  = (const float*)d_in[5];
    const float* c3b  = (const float*)d_in[6];
    const float* fc1w = (const float*)d_in[7];
    const float* fc1b = (const float*)d_in[8];
    const float* fc2w = (const float*)d_in[9];
    const float* fc2b = (const float*)d_in[10];
    const float* h1w  = (const float*)d_in[11];
    const float* h1b  = (const float*)d_in[12];
    const float* h2w  = (const float*)d_in[13];
    const float* h2b  = (const float*)d_in[14];
    const float* h3w  = (const float*)d_in[15];
    const float* h3b  = (const float*)d_in[16];
    const float* h4w  = (const float*)d_in[17];
    const float* h4b  = (const float*)d_in[18];
    float* out = (float*)d_out;

    // workspace layout (bytes):
    char* ws = (char*)d_ws;
    size_t o = 0;
    float* t1 = (float*)(ws + o); o += (size_t)NB*6*2401*4;      // 59,006,976
    float* t2 = (float*)(ws + o); o += (size_t)NB*4*484*4;       //  7,929,856
    float* t3 = (float*)(ws + o); o += (size_t)NB*200*4;         //    819,200
    float* f1 = (float*)(ws + o); o += (size_t)NB*400*4;         //  1,638,400
    half_t* g0h = (half_t*)(ws + o); o += (size_t)64*7*512*2;    //    458,752
    half_t* g0l = (half_t*)(ws + o); o += (size_t)64*7*512*2;
    half_t* w1h = (half_t*)(ws + o); o += (size_t)NR*7*9*512*2;  //  6,451,200
    half_t* w1l = (half_t*)(ws + o); o += (size_t)NR*7*9*512*2;
    half_t* w2h = (half_t*)(ws + o); o += (size_t)NR*5*6*512*2;  //  3,072,000
    half_t* w2l = (half_t*)(ws + o); o += (size_t)NR*5*6*512*2;
    half_t* w3h = (half_t*)(ws + o); o += (size_t)NR*3*3*512*2;  //    921,600
    half_t* w3l = (half_t*)(ws + o); o += (size_t)NR*3*3*512*2;
    half_t* w4h = (half_t*)(ws + o); o += (size_t)NR*2*1*512*2;  //    204,800
    half_t* w4l = (half_t*)(ws + o); o += (size_t)NR*2*1*512*2;  // total ~92.4MB

    // zero G0 planes (pad slots beyond K=200 must be 0; fc2 writes the rest)
    hipMemsetAsync(g0h, 0, (size_t)64*7*512*2*2, stream);

    // pre-split head weights into fragment-ordered f16 planes
    wsplit_k<<<dim3(17, NR), 256, 0, stream>>>(h1w, h2w, h3w, h4w,
        w1h, w1l, w2h, w2l, w3h, w3l, w4h, w4l);

    conv1_k<<<NB, 256, 0, stream>>>(x, c1w, c1b, t1);
    conv2_k<<<NB*4, 256, 0, stream>>>(t1, c2w, c2b, t2);
    conv3_k<<<NB, 256, 0, stream>>>(t2, c3w, c3b, t3);

    // fc1: [1024,200] x [200,400] -> f1 (f32)
    gemm_k<false><<<dim3(7, 8), 256, 0, stream>>>(
        t3, 200, fc1w, fc1b, f1, 400, NB, 400, 200, nullptr, nullptr);
    // fc2: [1024,400] x [400,200] -> G0 fragment planes (f16 hi/lo)
    gemm_k<true><<<dim3(4, 8), 256, 0, stream>>>(
        f1, 400, fc2w, fc2b, nullptr, 0, NB, 200, 400, g0h, g0l);

    // fused head chain, all 100 radicals
    head_k<<<dim3(8, NR), 256, 0, stream>>>(
        g0h, g0l, w1h, w1l, w2h, w2l, w3h, w3l, w4h, w4l,
        h1b, h2b, h3b, h4b, out);

    (void)in_sizes; (void)n_in; (void)out_size; (void)ws_size;
}

// Round 5
// 220.754 us; speedup vs baseline: 1.9440x; 1.1891x over previous
//
#include <hip/hip_runtime.h>

#define NB 1024
#define NR 100

typedef _Float16 half_t;
typedef half_t f16x8 __attribute__((ext_vector_type(8)));
typedef float f32x4 __attribute__((ext_vector_type(4)));

// fragment k-map used CONSISTENTLY for all A and B operands:
// k_local = g*4 + (j&3) + 16*(j>>2)   (g = lane>>4, j = elem 0..7)
__device__ __forceinline__ int kmap2(int g, int j) {
    return g*4 + (j & 3) + ((j >> 2) << 4);
}

// async global->LDS, 16B per lane; LDS dest = base + lane*16 (HW behavior)
#define GLDS(gsrc, ldst) \
    __builtin_amdgcn_global_load_lds( \
        (const __attribute__((address_space(1))) void*)(gsrc), \
        (__attribute__((address_space(3))) void*)(ldst), 16, 0, 0)

// ---------------------------------------------------------------------------
// conv1: x[B,1,98,98] -> out[B,6,49,49]   (conv 3x3 pad1 + relu + maxpool2)
// ---------------------------------------------------------------------------
__global__ __launch_bounds__(256) void conv1_k(const float* __restrict__ x,
        const float* __restrict__ w, const float* __restrict__ bias,
        float* __restrict__ out) {
    __shared__ float img[98*98];
    __shared__ float ws[54];
    __shared__ float bs[6];
    const int b = blockIdx.x;
    const int tid = threadIdx.x;
    const float* xb = x + (size_t)b * 9604;
    for (int i = tid; i < 2401; i += 256)
        ((float4*)img)[i] = ((const float4*)xb)[i];
    if (tid < 54) ws[tid] = w[tid];
    if (tid < 6) bs[tid] = bias[tid];
    __syncthreads();
    for (int pos = tid; pos < 2401; pos += 256) {
        const int py = pos / 49, px = pos % 49;
        const int y0 = 2*py - 1, x0 = 2*px - 1;
        float p[4][4];
        #pragma unroll
        for (int dy = 0; dy < 4; ++dy) {
            const int iy = y0 + dy;
            #pragma unroll
            for (int dx = 0; dx < 4; ++dx) {
                const int ix = x0 + dx;
                p[dy][dx] = (iy >= 0 && iy < 98 && ix >= 0 && ix < 98)
                            ? img[iy*98 + ix] : 0.f;
            }
        }
        #pragma unroll
        for (int c = 0; c < 6; ++c) {
            float v0 = bs[c], v1 = bs[c], v2 = bs[c], v3 = bs[c];
            #pragma unroll
            for (int ky = 0; ky < 3; ++ky) {
                #pragma unroll
                for (int kx = 0; kx < 3; ++kx) {
                    const float wv = ws[c*9 + ky*3 + kx];
                    v0 = fmaf(wv, p[ky  ][kx  ], v0);
                    v1 = fmaf(wv, p[ky  ][kx+1], v1);
                    v2 = fmaf(wv, p[ky+1][kx  ], v2);
                    v3 = fmaf(wv, p[ky+1][kx+1], v3);
                }
            }
            float m = fmaxf(fmaxf(v0, v1), fmaxf(v2, v3));
            out[((size_t)b*6 + c)*2401 + pos] = fmaxf(m, 0.f);
        }
    }
}

// ---------------------------------------------------------------------------
// conv2: in[B,6,49,49] -> out[B,4,22,22]  (conv 6x6 VALID + relu + maxpool2)
// ---------------------------------------------------------------------------
__global__ __launch_bounds__(256, 4) void conv2_k(const float* __restrict__ in,
        const float* __restrict__ w, const float* __restrict__ bias,
        float* __restrict__ out) {
    __shared__ float smc[6*27*28];
    __shared__ float ws[864];
    __shared__ float bs[4];
    const int blk = blockIdx.x;
    const int b  = blk >> 2;
    const int qy = (blk >> 1) & 1, qx = blk & 1;
    const int r0 = qy*22, c0 = qx*22;
    const int tid = threadIdx.x;
    const float* src = in + (size_t)b * 14406;
    for (int idx = tid; idx < 6*27*27; idx += 256) {
        const int ic  = idx / 729;
        const int rem = idx - ic*729;
        const int rr  = rem / 27;
        const int cc  = rem - rr*27;
        smc[ic*756 + rr*28 + cc] = src[ic*2401 + (r0+rr)*49 + c0 + cc];
    }
    for (int i = tid; i < 864; i += 256) ws[i] = w[i];
    if (tid < 4) bs[tid] = bias[tid];
    __syncthreads();
    if (tid < 242) {
        const int ocg = tid / 121;
        const int p   = tid - ocg*121;
        const int py  = p / 11, px = p - py*11;
        const int y0  = 2*py, x0 = 2*px;
        float acc[2][4];
        #pragma unroll
        for (int o = 0; o < 2; ++o) {
            const float bv = bs[ocg*2 + o];
            acc[o][0] = acc[o][1] = acc[o][2] = acc[o][3] = bv;
        }
        #pragma unroll
        for (int ic = 0; ic < 6; ++ic) {
            float pt[7][7];
            const float* basep = smc + ic*756 + y0*28 + x0;
            #pragma unroll
            for (int u = 0; u < 7; ++u) {
                const float* rb = basep + u*28;
                *(float2*)&pt[u][0] = *(const float2*)&rb[0];
                *(float2*)&pt[u][2] = *(const float2*)&rb[2];
                *(float2*)&pt[u][4] = *(const float2*)&rb[4];
                pt[u][6] = rb[6];
            }
            #pragma unroll
            for (int o = 0; o < 2; ++o) {
                const float* wp = ws + ((ocg*2 + o)*6 + ic)*36;
                #pragma unroll
                for (int ky = 0; ky < 6; ++ky) {
                    #pragma unroll
                    for (int kx = 0; kx < 6; ++kx) {
                        const float wv = wp[ky*6 + kx];
                        acc[o][0] = fmaf(wv, pt[ky  ][kx  ], acc[o][0]);
                        acc[o][1] = fmaf(wv, pt[ky  ][kx+1], acc[o][1]);
                        acc[o][2] = fmaf(wv, pt[ky+1][kx  ], acc[o][2]);
                        acc[o][3] = fmaf(wv, pt[ky+1][kx+1], acc[o][3]);
                    }
                }
            }
        }
        const int PY = qy*11 + py, PX = qx*11 + px;
        #pragma unroll
        for (int o = 0; o < 2; ++o) {
            const int oc = ocg*2 + o;
            float m = fmaxf(fmaxf(acc[o][0], acc[o][1]),
                            fmaxf(acc[o][2], acc[o][3]));
            out[(((size_t)b*4 + oc)*22 + PY)*22 + PX] = fmaxf(m, 0.f);
        }
    }
}

// ---------------------------------------------------------------------------
// conv3: in[B,4,22,22] -> out[B,200]
// ---------------------------------------------------------------------------
__global__ __launch_bounds__(256) void conv3_k(const float* __restrict__ in,
        const float* __restrict__ w, const float* __restrict__ bias,
        float* __restrict__ out) {
    __shared__ float sm[1936];
    __shared__ float ws[72];
    __shared__ float bs[2];
    const int b = blockIdx.x;
    const int tid = threadIdx.x;
    const float* src = in + (size_t)b * 1936;
    for (int i = tid; i < 484; i += 256)
        ((float4*)sm)[i] = ((const float4*)src)[i];
    if (tid < 72) ws[tid] = w[tid];
    if (tid < 2) bs[tid] = bias[tid];
    __syncthreads();
    if (tid < 200) {
        const int c = tid / 100;
        const int rem = tid % 100;
        const int py = rem / 10, px = rem % 10;
        const int y0 = 2*py, x0 = 2*px;
        float a0, a1, a2, a3;
        a0 = a1 = a2 = a3 = bs[c];
        #pragma unroll
        for (int ic = 0; ic < 4; ++ic) {
            float p[4][4];
            const float* base = sm + ic*484 + y0*22 + x0;
            #pragma unroll
            for (int u = 0; u < 4; ++u)
                #pragma unroll
                for (int v = 0; v < 4; ++v)
                    p[u][v] = base[u*22 + v];
            const float* wp = ws + (c*4 + ic)*9;
            #pragma unroll
            for (int ky = 0; ky < 3; ++ky) {
                #pragma unroll
                for (int kx = 0; kx < 3; ++kx) {
                    const float wv = wp[ky*3 + kx];
                    a0 = fmaf(wv, p[ky  ][kx  ], a0);
                    a1 = fmaf(wv, p[ky  ][kx+1], a1);
                    a2 = fmaf(wv, p[ky+1][kx  ], a2);
                    a3 = fmaf(wv, p[ky+1][kx+1], a3);
                }
            }
        }
        float m = fmaxf(fmaxf(a0, a1), fmaxf(a2, a3));
        out[(size_t)b*200 + tid] = fmaxf(m, 0.f);
    }
}

// ---------------------------------------------------------------------------
// f32 GEMM (fc1 / fc2), 128x64 tile. G0OUT: write packed f16 hi/lo fragment
// planes (B-fragment layout for the head kernel) instead of f32 C.
// ---------------------------------------------------------------------------
template<bool G0OUT>
__global__ __launch_bounds__(256, 4) void gemm_k(
        const float* __restrict__ A, int lda,
        const float* __restrict__ W, const float* __restrict__ bias,
        float* __restrict__ C, int ldc,
        int M, int N, int K,
        half_t* __restrict__ g0h, half_t* __restrict__ g0l) {
    __shared__ float As[32][132];
    __shared__ float Ws[32][64];
    const int m0 = blockIdx.y * 128;
    const int n0 = blockIdx.x * 64;
    const int tid = threadIdx.x;
    const int ti = tid >> 4, tj = tid & 15;
    float acc[8][4];
    #pragma unroll
    for (int i = 0; i < 8; ++i)
        #pragma unroll
        for (int j = 0; j < 4; ++j) acc[i][j] = 0.f;

    for (int k0 = 0; k0 < K; k0 += 32) {
        #pragma unroll
        for (int i = 0; i < 4; ++i) {
            const int f = tid + i*256;
            const int m = f >> 3, kg = f & 7;
            const int kk = kg*4;
            float4 v = make_float4(0.f, 0.f, 0.f, 0.f);
            if (k0 + kk < K)
                v = *(const float4*)(A + (long)(m0 + m)*lda + k0 + kk);
            As[kk+0][m] = v.x;
            As[kk+1][m] = v.y;
            As[kk+2][m] = v.z;
            As[kk+3][m] = v.w;
        }
        #pragma unroll
        for (int i = 0; i < 2; ++i) {
            const int f = tid + i*256;
            const int kk = f >> 4, cg = f & 15;
            const int n = n0 + cg*4;
            float4 v = make_float4(0.f, 0.f, 0.f, 0.f);
            if (k0 + kk < K) {
                const float* wp = W + (long)(k0 + kk)*N;
                if (n + 3 < N) v = *(const float4*)(wp + n);
                else {
                    if (n+0 < N) v.x = wp[n+0];
                    if (n+1 < N) v.y = wp[n+1];
                    if (n+2 < N) v.z = wp[n+2];
                }
            }
            *(float4*)&Ws[kk][cg*4] = v;
        }
        __syncthreads();
        #pragma unroll
        for (int kk = 0; kk < 32; ++kk) {
            float a[8], wv[4];
            *(float4*)&a[0] = *(const float4*)&As[kk][ti*8];
            *(float4*)&a[4] = *(const float4*)&As[kk][ti*8 + 4];
            *(float4*)&wv[0] = *(const float4*)&Ws[kk][tj*4];
            #pragma unroll
            for (int i = 0; i < 8; ++i)
                #pragma unroll
                for (int j = 0; j < 4; ++j)
                    acc[i][j] = fmaf(a[i], wv[j], acc[i][j]);
        }
        __syncthreads();
    }

    const int nb = n0 + tj*4;
    float bv[4] = {0.f, 0.f, 0.f, 0.f};
    #pragma unroll
    for (int e = 0; e < 4; ++e) if (nb + e < N) bv[e] = bias[nb + e];

    if (!G0OUT) {
        #pragma unroll
        for (int i = 0; i < 8; ++i) {
            const long m = m0 + ti*8 + i;
            if (nb + 3 < N) {
                float4 v;
                v.x = fmaxf(acc[i][0] + bv[0], 0.f);
                v.y = fmaxf(acc[i][1] + bv[1], 0.f);
                v.z = fmaxf(acc[i][2] + bv[2], 0.f);
                v.w = fmaxf(acc[i][3] + bv[3], 0.f);
                *(float4*)(C + m*(long)ldc + nb) = v;
            } else {
                #pragma unroll
                for (int j = 0; j < 4; ++j)
                    if (nb + j < N)
                        C[m*(long)ldc + nb + j] = fmaxf(acc[i][j] + bv[j], 0.f);
            }
        }
    } else {
        // write packed f16 hi/lo planes in B-fragment order:
        // idx = ((mb*7 + kc)*64 + (g<<4 | m&15))*8 + j,  k = kc*32 + kmap2(g,j)
        #pragma unroll
        for (int i = 0; i < 8; ++i) {
            const int m = m0 + ti*8 + i;
            #pragma unroll
            for (int j = 0; j < 4; ++j) {
                const int k = nb + j;
                if (k < N) {
                    const float v = fmaxf(acc[i][j] + bv[j], 0.f);
                    const half_t hi = (half_t)v;
                    const half_t lo = (half_t)(v - (float)hi);
                    const int kc = k >> 5, klo = k & 31;
                    const int h = klo >> 4, rm = klo & 15;
                    const int gg = rm >> 2, rr = rm & 3;
                    const size_t idx =
                        ((size_t)((m >> 4)*7 + kc)*64 + (gg << 4) + (m & 15))*8
                        + h*4 + rr;
                    g0h[idx] = hi;
                    g0l[idx] = lo;
                }
            }
        }
    }
}

// ---------------------------------------------------------------------------
// wsplit: all 4 head weight arrays f32 -> fragment-ordered f16 hi/lo planes.
// ---------------------------------------------------------------------------
__global__ __launch_bounds__(256) void wsplit_k(
        const float* __restrict__ w1, const float* __restrict__ w2,
        const float* __restrict__ w3, const float* __restrict__ w4,
        half_t* __restrict__ f1h, half_t* __restrict__ f1l,
        half_t* __restrict__ f2h, half_t* __restrict__ f2l,
        half_t* __restrict__ f3h, half_t* __restrict__ f3l,
        half_t* __restrict__ f4h, half_t* __restrict__ f4l) {
    __shared__ float lds[32*140];
    const int cx = blockIdx.x, r = blockIdx.y, tid = threadIdx.x;
    int K, N, KC, NF, kc;
    const float* src;
    half_t *dh, *dl;
    if (cx < 7)       { K=200; N=140; KC=7; NF=9; kc=cx;    src=w1; dh=f1h; dl=f1l; }
    else if (cx < 12) { K=140; N=84;  KC=5; NF=6; kc=cx-7;  src=w2; dh=f2h; dl=f2l; }
    else if (cx < 15) { K=84;  N=42;  KC=3; NF=3; kc=cx-12; src=w3; dh=f3h; dl=f3l; }
    else              { K=42;  N=4;   KC=2; NF=1; kc=cx-15; src=w4; dh=f4h; dl=f4l; }
    const float* sb = src + (size_t)r * K * N;
    for (int i = tid; i < 32*N; i += 256) {
        const int kk = i / N, n = i - kk*N;
        const int kg = kc*32 + kk;
        lds[kk*N + n] = (kg < K) ? sb[(size_t)kg*N + n] : 0.f;
    }
    __syncthreads();
    const size_t base = ((size_t)r*KC + kc)*NF*512;
    for (int e = tid; e < NF*512; e += 256) {
        const int nf = e >> 9, rem = e & 511;
        const int l = rem >> 3, j = rem & 7;
        const int g = l >> 4, c = l & 15;
        const int kl = kmap2(g, j);
        const int n = nf*16 + c;
        const float v = (n < N) ? lds[kl*N + n] : 0.f;
        const half_t hi = (half_t)v;
        const half_t lo = (half_t)(v - (float)hi);
        dh[base + (size_t)nf*512 + rem] = hi;
        dl[base + (size_t)nf*512 + rem] = lo;
    }
}

// ---------------------------------------------------------------------------
// head_k: per-radical chain 200->140->84->42->4 fused, split-f16 MFMA.
// v2: weights LDS-staged once per block (global_load_lds), XCD-swizzled grid
// so all 8 m-tile blocks of a radical share one XCD's L2.
// grid: 832 blocks 1D; c=bid&7 (XCD), k=bid>>3; r=(k>>3)*8+c, mt=k&7.
// ---------------------------------------------------------------------------
#define MFMA(a, b, c) __builtin_amdgcn_mfma_f32_16x16x32_f16(a, b, c, 0, 0, 0)

__global__ __launch_bounds__(256, 4) void head_k(
        const half_t* __restrict__ g0h, const half_t* __restrict__ g0l,
        const half_t* __restrict__ w1h, const half_t* __restrict__ w1l,
        const half_t* __restrict__ w2h, const half_t* __restrict__ w2l,
        const half_t* __restrict__ w3h, const half_t* __restrict__ w3l,
        const half_t* __restrict__ w4h, const half_t* __restrict__ w4l,
        const float* __restrict__ b1, const float* __restrict__ b2,
        const float* __restrict__ b3, const float* __restrict__ b4,
        float* __restrict__ out) {
    __shared__ half_t wb[18*512];   // 18 KB staging (max chunk: L1, 9 hi + 9 lo)
    __shared__ float bl[270];
    const int bid = blockIdx.x;
    const int cx  = bid & 7;
    const int kb  = bid >> 3;           // 0..103
    const int r   = ((kb >> 3) << 3) + cx;
    if (r >= NR) return;
    const int mt  = kb & 7;
    const int tid = threadIdx.x;
    if (tid < 140) bl[tid]       = b1[(size_t)r*140 + tid];
    if (tid < 84)  bl[140 + tid] = b2[(size_t)r*84  + tid];
    if (tid < 42)  bl[224 + tid] = b3[(size_t)r*42  + tid];
    if (tid < 4)   bl[266 + tid] = b4[(size_t)r*4   + tid];
    const int w = tid >> 6, l = tid & 63;
    const int g4 = ((l >> 4) & 3) * 4;
    const int mb0 = mt*8 + w*2;          // global m-block (16 batch rows each)
    const size_t loff = (size_t)l * 8;   // lane offset in halfs (16B)

    // ===================== L1: K=200 (7 chunks), N=140 (9 frags) ==========
    f32x4 a1[2][9] = {};
    for (int kc = 0; kc < 7; ++kc) {
        const half_t* hs = w1h + ((size_t)r*7 + kc)*9*512;
        const half_t* ls = w1l + ((size_t)r*7 + kc)*9*512;
        #pragma unroll
        for (int p0 = 0; p0 < 3; ++p0) {         // planes w, w+4, w+8
            const int p = w + p0*4;
            if (p < 9) {
                GLDS(hs + (size_t)p*512 + loff, wb + p*512);
                GLDS(ls + (size_t)p*512 + loff, wb + (9+p)*512);
            }
        }
        f16x8 bh[2], blo[2];
        #pragma unroll
        for (int mb = 0; mb < 2; ++mb) {
            const size_t bo = ((size_t)(mb0 + mb)*7 + kc)*512 + loff;
            bh[mb]  = *(const f16x8*)(g0h + bo);
            blo[mb] = *(const f16x8*)(g0l + bo);
        }
        __syncthreads();                          // stage (+bias) complete
        #pragma unroll
        for (int nf = 0; nf < 9; ++nf) {
            const f16x8 wh = *(const f16x8*)(wb + nf*512 + loff);
            const f16x8 wl = *(const f16x8*)(wb + (9+nf)*512 + loff);
            #pragma unroll
            for (int mb = 0; mb < 2; ++mb) {
                a1[mb][nf] = MFMA(wh, bh[mb],  a1[mb][nf]);
                a1[mb][nf] = MFMA(wh, blo[mb], a1[mb][nf]);
                a1[mb][nf] = MFMA(wl, bh[mb],  a1[mb][nf]);
            }
        }
        __syncthreads();                          // wb free for next chunk
    }
    // ---- convert a1 -> L2 B-fragments (bias+relu+split), N1=140 ----
    f16x8 b2h[2][5], b2l[2][5];
    #pragma unroll
    for (int kc = 0; kc < 5; ++kc)
        #pragma unroll
        for (int h = 0; h < 2; ++h) {
            const int nf = kc*2 + h;
            #pragma unroll
            for (int mb = 0; mb < 2; ++mb)
                #pragma unroll
                for (int rr = 0; rr < 4; ++rr) {
                    float v = 0.f;
                    if (nf < 9) {
                        const int n = nf*16 + g4 + rr;
                        v = (n < 140) ? fmaxf(a1[mb][nf][rr] + bl[n], 0.f) : 0.f;
                    }
                    const half_t hi = (half_t)v;
                    const half_t lo = (half_t)(v - (float)hi);
                    b2h[mb][kc][h*4+rr] = hi;
                    b2l[mb][kc][h*4+rr] = lo;
                }
        }
    // ===================== L2: K=140 (5 chunks), N=84 (6 frags) ===========
    f32x4 a2[2][6] = {};
    for (int kc = 0; kc < 5; ++kc) {
        const half_t* hs = w2h + ((size_t)r*5 + kc)*6*512;
        const half_t* ls = w2l + ((size_t)r*5 + kc)*6*512;
        #pragma unroll
        for (int p0 = 0; p0 < 2; ++p0) {         // planes w, w+4
            const int p = w + p0*4;
            if (p < 6) {
                GLDS(hs + (size_t)p*512 + loff, wb + p*512);
                GLDS(ls + (size_t)p*512 + loff, wb + (6+p)*512);
            }
        }
        __syncthreads();
        #pragma unroll
        for (int nf = 0; nf < 6; ++nf) {
            const f16x8 wh = *(const f16x8*)(wb + nf*512 + loff);
            const f16x8 wl = *(const f16x8*)(wb + (6+nf)*512 + loff);
            #pragma unroll
            for (int mb = 0; mb < 2; ++mb) {
                a2[mb][nf] = MFMA(wh, b2h[mb][kc], a2[mb][nf]);
                a2[mb][nf] = MFMA(wh, b2l[mb][kc], a2[mb][nf]);
                a2[mb][nf] = MFMA(wl, b2h[mb][kc], a2[mb][nf]);
            }
        }
        __syncthreads();
    }
    // ---- convert a2 -> L3 B-fragments, N2=84 ----
    f16x8 b3h[2][3], b3l[2][3];
    #pragma unroll
    for (int kc = 0; kc < 3; ++kc)
        #pragma unroll
        for (int h = 0; h < 2; ++h) {
            const int nf = kc*2 + h;
            #pragma unroll
            for (int mb = 0; mb < 2; ++mb)
                #pragma unroll
                for (int rr = 0; rr < 4; ++rr) {
                    float v = 0.f;
                    if (nf < 6) {
                        const int n = nf*16 + g4 + rr;
                        v = (n < 84) ? fmaxf(a2[mb][nf][rr] + bl[140 + n], 0.f) : 0.f;
                    }
                    const half_t hi = (half_t)v;
                    const half_t lo = (half_t)(v - (float)hi);
                    b3h[mb][kc][h*4+rr] = hi;
                    b3l[mb][kc][h*4+rr] = lo;
                }
        }
    // ===================== L3: K=84 (3 chunks), N=42 (3 frags) ============
    f32x4 a3[2][3] = {};
    for (int kc = 0; kc < 3; ++kc) {
        const half_t* hs = w3h + ((size_t)r*3 + kc)*3*512;
        const half_t* ls = w3l + ((size_t)r*3 + kc)*3*512;
        {
            const int p = w;                      // planes 0..2 (wave 3 idle)
            if (p < 3) {
                GLDS(hs + (size_t)p*512 + loff, wb + p*512);
                GLDS(ls + (size_t)p*512 + loff, wb + (3+p)*512);
            }
        }
        __syncthreads();
        #pragma unroll
        for (int nf = 0; nf < 3; ++nf) {
            const f16x8 wh = *(const f16x8*)(wb + nf*512 + loff);
            const f16x8 wl = *(const f16x8*)(wb + (3+nf)*512 + loff);
            #pragma unroll
            for (int mb = 0; mb < 2; ++mb) {
                a3[mb][nf] = MFMA(wh, b3h[mb][kc], a3[mb][nf]);
                a3[mb][nf] = MFMA(wh, b3l[mb][kc], a3[mb][nf]);
                a3[mb][nf] = MFMA(wl, b3h[mb][kc], a3[mb][nf]);
            }
        }
        __syncthreads();
    }
    // ---- convert a3 -> L4 B-fragments, N3=42 ----
    f16x8 b4h[2][2], b4l[2][2];
    #pragma unroll
    for (int kc = 0; kc < 2; ++kc)
        #pragma unroll
        for (int h = 0; h < 2; ++h) {
            const int nf = kc*2 + h;
            #pragma unroll
            for (int mb = 0; mb < 2; ++mb)
                #pragma unroll
                for (int rr = 0; rr < 4; ++rr) {
                    float v = 0.f;
                    if (nf < 3) {
                        const int n = nf*16 + g4 + rr;
                        v = (n < 42) ? fmaxf(a3[mb][nf][rr] + bl[224 + n], 0.f) : 0.f;
                    }
                    const half_t hi = (half_t)v;
                    const half_t lo = (half_t)(v - (float)hi);
                    b4h[mb][kc][h*4+rr] = hi;
                    b4l[mb][kc][h*4+rr] = lo;
                }
        }
    // ===================== L4: K=42 (2 chunks), N=4 — direct global =======
    f32x4 a4[2] = {};
    #pragma unroll
    for (int kc = 0; kc < 2; ++kc) {
        const size_t wo = ((size_t)r*2 + kc)*512 + loff;
        const f16x8 wh = *(const f16x8*)(w4h + wo);
        const f16x8 wl = *(const f16x8*)(w4l + wo);
        #pragma unroll
        for (int mb = 0; mb < 2; ++mb) {
            a4[mb] = MFMA(wh, b4h[mb][kc], a4[mb]);
            a4[mb] = MFMA(wh, b4l[mb][kc], a4[mb]);
            a4[mb] = MFMA(wl, b4h[mb][kc], a4[mb]);
        }
    }
    // epilogue: rows 0..3 live in lane group g==0 (row = g*4+reg)
    if ((l >> 4) == 0) {
        #pragma unroll
        for (int mb = 0; mb < 2; ++mb) {
            const int b = (mb0 + mb)*16 + (l & 15);
            float4 o;
            o.x = a4[mb][0] + bl[266];
            o.y = a4[mb][1] + bl[267];
            o.z = a4[mb][2] + bl[268];
            o.w = a4[mb][3] + bl[269];
            *(float4*)(out + (size_t)b*400 + r*4) = o;
        }
    }
}

extern "C" void kernel_launch(void* const* d_in, const int* in_sizes, int n_in,
                              void* d_out, int out_size, void* d_ws, size_t ws_size,
                              hipStream_t stream) {
    const float* x    = (const float*)d_in[0];
    const float* c1w  = (const float*)d_in[1];
    const float* c1b  = (const float*)d_in[2];
    const float* c2w  = (const float*)d_in[3];
    const float* c2b  = (const float*)d_in[4];
    const float* c3w  = (const float*)d_in[5];
    const float* c3b  = (const float*)d_in[6];
    const float* fc1w = (const float*)d_in[7];
    const float* fc1b = (const float*)d_in[8];
    const float* fc2w = (const float*)d_in[9];
    const float* fc2b = (const float*)d_in[10];
    const float* h1w  = (const float*)d_in[11];
    const float* h1b  = (const float*)d_in[12];
    const float* h2w  = (const float*)d_in[13];
    const float* h2b  = (const float*)d_in[14];
    const float* h3w  = (const float*)d_in[15];
    const float* h3b  = (const float*)d_in[16];
    const float* h4w  = (const float*)d_in[17];
    const float* h4b  = (const float*)d_in[18];
    float* out = (float*)d_out;

    // workspace layout (bytes):
    char* ws = (char*)d_ws;
    size_t o = 0;
    float* t1 = (float*)(ws + o); o += (size_t)NB*6*2401*4;      // 59,006,976
    float* t2 = (float*)(ws + o); o += (size_t)NB*4*484*4;       //  7,929,856
    float* t3 = (float*)(ws + o); o += (size_t)NB*200*4;         //    819,200
    float* f1 = (float*)(ws + o); o += (size_t)NB*400*4;         //  1,638,400
    half_t* g0h = (half_t*)(ws + o); o += (size_t)64*7*512*2;    //    458,752
    half_t* g0l = (half_t*)(ws + o); o += (size_t)64*7*512*2;
    half_t* w1h = (half_t*)(ws + o); o += (size_t)NR*7*9*512*2;  //  6,451,200
    half_t* w1l = (half_t*)(ws + o); o += (size_t)NR*7*9*512*2;
    half_t* w2h = (half_t*)(ws + o); o += (size_t)NR*5*6*512*2;  //  3,072,000
    half_t* w2l = (half_t*)(ws + o); o += (size_t)NR*5*6*512*2;
    half_t* w3h = (half_t*)(ws + o); o += (size_t)NR*3*3*512*2;  //    921,600
    half_t* w3l = (half_t*)(ws + o); o += (size_t)NR*3*3*512*2;
    half_t* w4h = (half_t*)(ws + o); o += (size_t)NR*2*1*512*2;  //    204,800
    half_t* w4l = (half_t*)(ws + o); o += (size_t)NR*2*1*512*2;  // total ~92.4MB

    // zero G0 planes (pad slots beyond K=200 must be 0; fc2 writes the rest)
    hipMemsetAsync(g0h, 0, (size_t)64*7*512*2*2, stream);

    // pre-split head weights into fragment-ordered f16 planes
    wsplit_k<<<dim3(17, NR), 256, 0, stream>>>(h1w, h2w, h3w, h4w,
        w1h, w1l, w2h, w2l, w3h, w3l, w4h, w4l);

    conv1_k<<<NB, 256, 0, stream>>>(x, c1w, c1b, t1);
    conv2_k<<<NB*4, 256, 0, stream>>>(t1, c2w, c2b, t2);
    conv3_k<<<NB, 256, 0, stream>>>(t2, c3w, c3b, t3);

    // fc1: [1024,200] x [200,400] -> f1 (f32)
    gemm_k<false><<<dim3(7, 8), 256, 0, stream>>>(
        t3, 200, fc1w, fc1b, f1, 400, NB, 400, 200, nullptr, nullptr);
    // fc2: [1024,400] x [400,200] -> G0 fragment planes (f16 hi/lo)
    gemm_k<true><<<dim3(4, 8), 256, 0, stream>>>(
        f1, 400, fc2w, fc2b, nullptr, 0, NB, 200, 400, g0h, g0l);

    // fused head chain, all 100 radicals (XCD-swizzled 1D grid, 32 pad blocks)
    head_k<<<832, 256, 0, stream>>>(
        g0h, g0l, w1h, w1l, w2h, w2l, w3h, w3l, w4h, w4l,
        h1b, h2b, h3b, h4b, out);

    (void)in_sizes; (void)n_in; (void)out_size; (void)ws_size;
}